// Round 2
// baseline (585.928 us; speedup 1.0000x reference)
//
#include <hip/hip_runtime.h>

// RegionSelector fused: sampling_map [B,1,512,512] f32 -> [B,1,2] int32
// (row,col) argmax over 3x3 sliding-window sums of 4x4 grid-cell means.
// GRID=4, WIN=3, TOPK=1 -> n=2, cell = 128x128.
//
// Single kernel: 16 blocks per batch each reduce a 32x512 strip to 4
// grid-column partials, publish via release flag; the rb==0 block of each
// batch acquire-spins on its 15 siblings and computes the argmax epilogue.
// Producers never spin -> no deadlock regardless of scheduling/co-residency.

#define H 512
#define W 512
#define ROWS_PER_BLOCK 32
#define BLOCKS_PER_BATCH 16  // 512 / 32
#define MAGIC 0x5CA1AB1Eu    // != 0xAAAAAAAA poison

__global__ __launch_bounds__(256, 8) void region_select_fused(
    const float* __restrict__ src, float* __restrict__ partial,
    unsigned int* __restrict__ flags, int* __restrict__ out) {
  const int bid = blockIdx.x;
  const int b = bid >> 4;
  const int rb = bid & 15;
  const int t = threadIdx.x;

  // ---- strip reduction: 32 rows x 512 cols = 4096 float4 ----
  const float4* base = (const float4*)(src + (size_t)b * (H * W) +
                                       (size_t)rb * ROWS_PER_BLOCK * W);
  // f = t + 256*k; col4 = f & 127 = t & 127 is constant per thread, so each
  // thread's grid column gc = (t & 127) >> 5 is fixed -> one scalar acc.
  float acc = 0.0f;
#pragma unroll
  for (int k = 0; k < 16; ++k) {
    float4 v = base[t + 256 * k];
    acc += (v.x + v.y) + (v.z + v.w);
  }

  __shared__ float lds[256];
  lds[t] = acc;
  __syncthreads();
  if (t < 128) lds[t] += lds[t + 128];
  __syncthreads();
#pragma unroll
  for (int off = 16; off > 0; off >>= 1) {
    if (t < 128 && (t & 31) < off) lds[t] += lds[t + off];
    __syncthreads();
  }

  // ---- publish: partials then release flag (device scope) ----
  if (t < 4) partial[bid * 4 + t] = lds[t * 32];
  __threadfence();   // storing threads order their writes to device scope
  __syncthreads();   // fence retired before flag is raised
  if (t == 0)
    __hip_atomic_store(&flags[bid], MAGIC, __ATOMIC_RELEASE,
                       __HIP_MEMORY_SCOPE_AGENT);

  if (rb != 0) return;

  // ---- epilogue (one block per batch): wait for 15 siblings ----
  if (t < BLOCKS_PER_BATCH - 1) {
    while (__hip_atomic_load(&flags[b * BLOCKS_PER_BATCH + 1 + t],
                             __ATOMIC_ACQUIRE,
                             __HIP_MEMORY_SCOPE_AGENT) != MAGIC) {
      __builtin_amdgcn_s_sleep(1);
    }
  }
  __syncthreads();  // all flags observed; acquires ordered before reads below

  if (t < 64) lds[t] = partial[b * 64 + t];  // [rb][gc] = lds[rb*4+gc]
  __syncthreads();

  if (t == 0) {
    // Cell sums S[gr][gc] = sum over 4 row-strips of that cell.
    float S[4][4];
#pragma unroll
    for (int gr = 0; gr < 4; ++gr)
#pragma unroll
      for (int gc = 0; gc < 4; ++gc) {
        float s = 0.0f;
#pragma unroll
        for (int j = 0; j < 4; ++j) s += lds[(gr * 4 + j) * 4 + gc];
        S[gr][gc] = s;
      }
    // 3x3 window sums, n=2; strict '>' keeps lowest index on ties
    // (matches jax.lax.top_k). Mean's 1/16384 scale is argmax-invariant.
    float best = -__builtin_inff();
    int bi = 0;
#pragma unroll
    for (int i = 0; i < 2; ++i)
#pragma unroll
      for (int j = 0; j < 2; ++j) {
        float ws = 0.0f;
#pragma unroll
        for (int di = 0; di < 3; ++di)
#pragma unroll
          for (int dj = 0; dj < 3; ++dj) ws += S[i + di][j + dj];
        if (ws > best) {
          best = ws;
          bi = i * 2 + j;
        }
      }
    out[b * 2 + 0] = bi >> 1;  // row
    out[b * 2 + 1] = bi & 1;   // col
  }
}

extern "C" void kernel_launch(void* const* d_in, const int* in_sizes, int n_in,
                              void* d_out, int out_size, void* d_ws,
                              size_t ws_size, hipStream_t stream) {
  const float* src = (const float*)d_in[0];
  int* out = (int*)d_out;
  const int B = in_sizes[0] / (H * W);

  float* partial = (float*)d_ws;                       // B*64 floats
  unsigned int* flags = (unsigned int*)(partial + B * 64);  // B*16 uints

  region_select_fused<<<B * BLOCKS_PER_BATCH, 256, 0, stream>>>(src, partial,
                                                                flags, out);
}

// Round 3
// 364.272 us; speedup vs baseline: 1.6085x; 1.6085x over previous
//
#include <hip/hip_runtime.h>

// RegionSelector fused: sampling_map [B,1,512,512] f32 -> [B,1,2] int32
// (row,col) argmax over 3x3 sliding-window sums of 4x4 grid-cell means.
// GRID=4, WIN=3, TOPK=1 -> n=2, cell = 128x128.
//
// Single kernel: 16 blocks per batch each reduce a 32x512 strip to 4
// grid-column partials, publish via release flag; the rb==0 block of each
// batch waits on its 15 siblings and computes the argmax epilogue.
//
// R2 lesson: ACQUIRE loads in the spin loop emit cache-invalidate
// maintenance every iteration (agent-scope acquire on CDNA4) -> L1/L2
// invalidation storm -> 30x slowdown (147 GB/s effective). Spin RELAXED
// (coherent-point load, no maintenance), one ACQUIRE after observing MAGIC.

#define H 512
#define W 512
#define ROWS_PER_BLOCK 32
#define BLOCKS_PER_BATCH 16  // 512 / 32
#define MAGIC 0x5CA1AB1Eu    // != 0xAAAAAAAA poison, != 0

__global__ __launch_bounds__(256, 8) void region_select_fused(
    const float* __restrict__ src, float* __restrict__ partial,
    unsigned int* __restrict__ flags, int* __restrict__ out) {
  const int bid = blockIdx.x;
  const int b = bid >> 4;
  const int rb = bid & 15;
  const int t = threadIdx.x;

  // ---- strip reduction: 32 rows x 512 cols = 4096 float4 ----
  const float4* base = (const float4*)(src + (size_t)b * (H * W) +
                                       (size_t)rb * ROWS_PER_BLOCK * W);
  // f = t + 256*k; col4 = f & 127 = t & 127 is constant per thread, so each
  // thread's grid column gc = (t & 127) >> 5 is fixed -> one scalar acc.
  float acc = 0.0f;
#pragma unroll
  for (int k = 0; k < 16; ++k) {
    float4 v = base[t + 256 * k];
    acc += (v.x + v.y) + (v.z + v.w);
  }

  __shared__ float lds[256];
  lds[t] = acc;
  __syncthreads();
  if (t < 128) lds[t] += lds[t + 128];
  __syncthreads();
#pragma unroll
  for (int off = 16; off > 0; off >>= 1) {
    if (t < 128 && (t & 31) < off) lds[t] += lds[t + off];
    __syncthreads();
  }

  // ---- publish: partial stores drained by the barrier (vmcnt(0) before
  // s_barrier), then a single release-store of the flag by t0. ----
  if (t < 4) partial[bid * 4 + t] = lds[t * 32];
  __syncthreads();
  if (t == 0) {
    __threadfence();  // agent-scope release ordering for the block's stores
    __hip_atomic_store(&flags[bid], MAGIC, __ATOMIC_RELEASE,
                       __HIP_MEMORY_SCOPE_AGENT);
  }

  if (rb != 0) return;

  // ---- epilogue (one block per batch): wait for 15 siblings ----
  if (t < BLOCKS_PER_BATCH - 1) {
    const unsigned int* f = &flags[b * BLOCKS_PER_BATCH + 1 + t];
    // RELAXED spin: coherent-point dword load, NO per-iteration cache
    // invalidation. s_sleep(8) = ~512 cyc backoff keeps load rate tiny.
    while (__hip_atomic_load(f, __ATOMIC_RELAXED,
                             __HIP_MEMORY_SCOPE_AGENT) != MAGIC) {
      __builtin_amdgcn_s_sleep(8);
    }
    // One acquire to order/invalidate before reading the partials.
    (void)__hip_atomic_load(f, __ATOMIC_ACQUIRE, __HIP_MEMORY_SCOPE_AGENT);
  }
  __syncthreads();  // all flags observed + acquires retired

  if (t < 64) lds[t] = partial[b * 64 + t];  // [rb][gc] = lds[rb*4+gc]
  __syncthreads();

  if (t == 0) {
    // Cell sums S[gr][gc] = sum over the 4 row-strips of that cell.
    float S[4][4];
#pragma unroll
    for (int gr = 0; gr < 4; ++gr)
#pragma unroll
      for (int gc = 0; gc < 4; ++gc) {
        float s = 0.0f;
#pragma unroll
        for (int j = 0; j < 4; ++j) s += lds[(gr * 4 + j) * 4 + gc];
        S[gr][gc] = s;
      }
    // 3x3 window sums, n=2; strict '>' keeps lowest index on ties
    // (matches jax.lax.top_k). Mean's 1/16384 scale is argmax-invariant.
    float best = -__builtin_inff();
    int bi = 0;
#pragma unroll
    for (int i = 0; i < 2; ++i)
#pragma unroll
      for (int j = 0; j < 2; ++j) {
        float ws = 0.0f;
#pragma unroll
        for (int di = 0; di < 3; ++di)
#pragma unroll
          for (int dj = 0; dj < 3; ++dj) ws += S[i + di][j + dj];
        if (ws > best) {
          best = ws;
          bi = i * 2 + j;
        }
      }
    out[b * 2 + 0] = bi >> 1;  // row
    out[b * 2 + 1] = bi & 1;   // col
  }
}

extern "C" void kernel_launch(void* const* d_in, const int* in_sizes, int n_in,
                              void* d_out, int out_size, void* d_ws,
                              size_t ws_size, hipStream_t stream) {
  const float* src = (const float*)d_in[0];
  int* out = (int*)d_out;
  const int B = in_sizes[0] / (H * W);

  float* partial = (float*)d_ws;                            // B*64 floats
  unsigned int* flags = (unsigned int*)(partial + B * 64);  // B*16 uints

  region_select_fused<<<B * BLOCKS_PER_BATCH, 256, 0, stream>>>(src, partial,
                                                                flags, out);
}

// Round 4
// 288.404 us; speedup vs baseline: 2.0316x; 1.2631x over previous
//
#include <hip/hip_runtime.h>

// RegionSelector fused (last-block ticket): [B,1,512,512] f32 ->
// [B,1,2] int32 (row,col) argmax over 3x3 window sums of 4x4 grid-cell means.
// GRID=4, WIN=3 -> n=2, cell = 128x128.
//
// Sync history: R2 per-iteration ACQUIRE spin -> L2 invalidation storm
// (457 us). R3 RELAXED spin -> stale-line eventual-visibility stall (233 us).
// R4: NO polling. Each block's t0 does one ACQ_REL atomicAdd on a per-batch
// counter (RMW resolves at the coherence point -> last arrival knows
// instantly); the 16th block runs the epilogue. Counter zeroed by a tiny
// hipMemsetAsync node (capture-legal).

#define H 512
#define W 512
#define ROWS_PER_BLOCK 32
#define BPB 16  // blocks per batch = 512/32

__global__ __launch_bounds__(256, 8) void region_select_fused(
    const float* __restrict__ src, float* __restrict__ partial,
    unsigned int* __restrict__ cnt, int* __restrict__ out) {
  const int bid = blockIdx.x;
  const int b = bid >> 4;
  const int t = threadIdx.x;

  // ---- strip reduction: 32 rows x 512 cols = 4096 float4 ----
  const float4* base = (const float4*)(src + (size_t)b * (H * W) +
                                       (size_t)(bid & 15) * ROWS_PER_BLOCK * W);
  // f = t + 256*k; col4 = f & 127 = t & 127 constant per thread -> each
  // thread's grid column gc = (t & 127) >> 5 is fixed; every 32-lane
  // half-wave shares one gc -> shuffle-reduce within width-32 segments.
  float acc = 0.0f;
#pragma unroll
  for (int k = 0; k < 16; ++k) {
    float4 v = base[t + 256 * k];
    acc += (v.x + v.y) + (v.z + v.w);
  }
#pragma unroll
  for (int off = 16; off > 0; off >>= 1) acc += __shfl_down(acc, off, 32);

  __shared__ float seg[8];
  __shared__ float pbuf[64];
  __shared__ int is_last;
  const int lane = t & 63;
  const int wave = t >> 6;
  if ((lane & 31) == 0) seg[wave * 2 + (lane >> 5)] = acc;
  __syncthreads();
  // seg entry e=(wave*2+half) has gc = (wave&1)*2+half -> gc g = seg[g]+seg[g+4]
  if (t < 4) partial[bid * 4 + t] = seg[t] + seg[t + 4];
  __syncthreads();  // barrier implies vmcnt(0): partial stores are in L2

  if (t == 0) {
    // Release: wbl2 flushes this XCD's partials to the coherence point.
    // RMW executes at the coherence point: last arrival learns instantly.
    unsigned int old = __hip_atomic_fetch_add(&cnt[b], 1u, __ATOMIC_ACQ_REL,
                                              __HIP_MEMORY_SCOPE_AGENT);
    is_last = (old == BPB - 1);  // acquire: caches invalidated for epilogue
  }
  __syncthreads();
  if (!is_last) return;

  // ---- epilogue: only the 16th-arriving block of this batch ----
  if (t < 64) pbuf[t] = partial[b * 64 + t];  // [rb][gc] = pbuf[rb*4+gc]
  __syncthreads();

  if (t == 0) {
    float S[4][4];
#pragma unroll
    for (int gr = 0; gr < 4; ++gr)
#pragma unroll
      for (int gc = 0; gc < 4; ++gc) {
        float s = 0.0f;
#pragma unroll
        for (int j = 0; j < 4; ++j) s += pbuf[(gr * 4 + j) * 4 + gc];
        S[gr][gc] = s;
      }
    // 3x3 window sums, n=2; strict '>' keeps lowest index on ties
    // (matches jax.lax.top_k). Mean's 1/16384 scale is argmax-invariant.
    float best = -__builtin_inff();
    int bi = 0;
#pragma unroll
    for (int i = 0; i < 2; ++i)
#pragma unroll
      for (int j = 0; j < 2; ++j) {
        float ws = 0.0f;
#pragma unroll
        for (int di = 0; di < 3; ++di)
#pragma unroll
          for (int dj = 0; dj < 3; ++dj) ws += S[i + di][j + dj];
        if (ws > best) {
          best = ws;
          bi = i * 2 + j;
        }
      }
    out[b * 2 + 0] = bi >> 1;  // row
    out[b * 2 + 1] = bi & 1;   // col
  }
}

extern "C" void kernel_launch(void* const* d_in, const int* in_sizes, int n_in,
                              void* d_out, int out_size, void* d_ws,
                              size_t ws_size, hipStream_t stream) {
  const float* src = (const float*)d_in[0];
  int* out = (int*)d_out;
  const int B = in_sizes[0] / (H * W);

  float* partial = (float*)d_ws;                        // B*64 floats
  unsigned int* cnt = (unsigned int*)(partial + B * 64);  // B uints

  // d_ws is poisoned 0xAA before every launch -> zero the ticket counters.
  hipMemsetAsync(cnt, 0, B * sizeof(unsigned int), stream);
  region_select_fused<<<B * BPB, 256, 0, stream>>>(src, partial, cnt, out);
}

// Round 5
// 186.433 us; speedup vs baseline: 3.1428x; 1.5470x over previous
//
#include <hip/hip_runtime.h>

// RegionSelector, zero-sync single kernel: [B,1,512,512] f32 -> [B,1,2] int32
// (row,col) argmax over 3x3 window sums of 4x4 grid-cell means.
// GRID=4, WIN=3 -> n=2, cell = 128x128 (mean scale argmax-invariant -> sums).
//
// History: every cross-workgroup sync variant paid 100-400us in CDNA4
// device-scope cache maintenance (R2 acquire-spin 457us, R3 relaxed-spin
// stale-line 233us, R4 ACQ_REL ticket 152us). R5: one block per batch ->
// NO partials, NO flags, NO atomics, NO d_ws. 128 blocks x 1024 threads;
// 16 waves/block keep ~256KB of loads in flight per CU, enough to pull the
// per-CU HBM share even with half the CUs idle.

#define H 512
#define W 512

__global__ __launch_bounds__(1024) void region_select_block(
    const float* __restrict__ src, int* __restrict__ out) {
  const int b = blockIdx.x;
  const int t = threadIdx.x;
  const float4* base = (const float4*)(src + (size_t)b * (H * W));

  // Batch = 65536 float4. Phase p = grid row band (128 rows = 16384 float4).
  // f = p*16384 + t + 1024*k: col4 = f & 127 = t & 127 (constant per thread)
  // -> each thread's grid column gc = (t&127)>>5 is fixed; each phase is one
  // grid row -> 4 scalar accumulators, no indexed arrays.
  float acc[4];
#pragma unroll
  for (int p = 0; p < 4; ++p) {
    float s = 0.0f;
#pragma unroll
    for (int k = 0; k < 16; ++k) {
      float4 v = base[p * 16384 + t + 1024 * k];
      s += (v.x + v.y) + (v.z + v.w);
    }
    acc[p] = s;
  }

  // Within a 32-lane segment all lanes share gc (seg*32 % 128 = (seg&3)*32).
#pragma unroll
  for (int p = 0; p < 4; ++p)
#pragma unroll
    for (int off = 16; off > 0; off >>= 1)
      acc[p] += __shfl_down(acc[p], off, 32);

  __shared__ float seg_sums[32][4];  // [segment][gr]; segment gc = seg & 3
  __shared__ float S[16];            // cell sums [gr*4+gc]
  const int seg = t >> 5;
  if ((t & 31) == 0) {
#pragma unroll
    for (int p = 0; p < 4; ++p) seg_sums[seg][p] = acc[p];
  }
  __syncthreads();

  if (t < 16) {
    const int gr = t >> 2, gc = t & 3;
    float s = 0.0f;
#pragma unroll
    for (int j = 0; j < 8; ++j) s += seg_sums[j * 4 + gc][gr];
    S[t] = s;
  }
  __syncthreads();

  if (t == 0) {
    // 3x3 window sums, n=2; strict '>' keeps lowest index on ties
    // (matches jax.lax.top_k).
    float best = -__builtin_inff();
    int bi = 0;
#pragma unroll
    for (int i = 0; i < 2; ++i)
#pragma unroll
      for (int j = 0; j < 2; ++j) {
        float ws = 0.0f;
#pragma unroll
        for (int di = 0; di < 3; ++di)
#pragma unroll
          for (int dj = 0; dj < 3; ++dj) ws += S[(i + di) * 4 + (j + dj)];
        if (ws > best) {
          best = ws;
          bi = i * 2 + j;
        }
      }
    out[b * 2 + 0] = bi >> 1;  // row
    out[b * 2 + 1] = bi & 1;   // col
  }
}

extern "C" void kernel_launch(void* const* d_in, const int* in_sizes, int n_in,
                              void* d_out, int out_size, void* d_ws,
                              size_t ws_size, hipStream_t stream) {
  const float* src = (const float*)d_in[0];
  int* out = (int*)d_out;
  const int B = in_sizes[0] / (H * W);

  region_select_block<<<B, 1024, 0, stream>>>(src, out);
}